// Round 3
// baseline (5457.229 us; speedup 1.0000x reference)
//
#include <hip/hip_runtime.h>

#define D 128
#define TM 16

// ---------------- CSR build ----------------

__global__ void hist_kernel(const int* __restrict__ dst, int* __restrict__ deg, int E) {
    int i = blockIdx.x * blockDim.x + threadIdx.x;
    if (i < E) atomicAdd(&deg[dst[i]], 1);
}

// Two-level scan: scan1 (per-block excl scan + block sums), scan2 (scan block
// sums, single block), scan3 (add base, emit row_start/cursor/inv_deg).

__global__ void scan1_kernel(const int* __restrict__ deg, int* __restrict__ local_excl,
                             int* __restrict__ blocksum, int n) {
    __shared__ int tmp[1024];
    int i = blockIdx.x * 1024 + threadIdx.x;
    int v = (i < n) ? deg[i] : 0;
    tmp[threadIdx.x] = v;
    __syncthreads();
    for (int off = 1; off < 1024; off <<= 1) {
        int t = 0;
        if (threadIdx.x >= off) t = tmp[threadIdx.x - off];
        __syncthreads();
        if (threadIdx.x >= off) tmp[threadIdx.x] += t;
        __syncthreads();
    }
    int incl = tmp[threadIdx.x];
    if (i < n) local_excl[i] = incl - v;
    if (threadIdx.x == 1023) blocksum[blockIdx.x] = tmp[1023];
}

__global__ void scan2_kernel(int* __restrict__ blocksum, int nb) {
    __shared__ int tmp[1024];
    int v = (threadIdx.x < nb) ? blocksum[threadIdx.x] : 0;
    tmp[threadIdx.x] = v;
    __syncthreads();
    for (int off = 1; off < 1024; off <<= 1) {
        int t = 0;
        if (threadIdx.x >= off) t = tmp[threadIdx.x - off];
        __syncthreads();
        if (threadIdx.x >= off) tmp[threadIdx.x] += t;
        __syncthreads();
    }
    if (threadIdx.x < nb) blocksum[threadIdx.x] = tmp[threadIdx.x] - v;  // exclusive
}

__global__ void scan3_kernel(const int* __restrict__ deg, const int* __restrict__ local_excl,
                             const int* __restrict__ blocksum, int* __restrict__ row_start,
                             int* __restrict__ cursor, float* __restrict__ inv_deg,
                             int n, int n_edges) {
    int i = blockIdx.x * 1024 + threadIdx.x;
    if (i < n) {
        int rs = local_excl[i] + blocksum[blockIdx.x];
        row_start[i] = rs;
        cursor[i]    = rs;
        inv_deg[i]   = 1.0f / fmaxf((float)deg[i], 1.0f);
    }
    if (i == 0) row_start[n] = n_edges;
}

// csr[] holds BYTE offsets of the source row (src * D * 4) to cut per-gather
// address VALU in the hot layer kernel.
__global__ void scatter_kernel(const int* __restrict__ src, const int* __restrict__ dst,
                               int* __restrict__ cursor, int* __restrict__ csr, int E) {
    int i = blockIdx.x * blockDim.x + threadIdx.x;
    if (i < E) {
        int d = dst[i];
        int p = atomicAdd(&cursor[d], 1);
        csr[p] = src[i] << 9;   // * 512 bytes per row
    }
}

// ---------------- weight transpose (W[l][f][k] -> Wt[l][k][f]) ----------------

__global__ void transpose_w(const float* __restrict__ Wl, const float* __restrict__ Wr,
                            float* __restrict__ Wlt, float* __restrict__ Wrt, int total) {
    int i = blockIdx.x * blockDim.x + threadIdx.x;
    if (i < total) {
        int l = i >> 14;
        int r = i & 16383;
        int f = r >> 7;
        int k = r & 127;
        int o = (l << 14) + (k << 7) + f;
        Wlt[o] = Wl[i];
        Wrt[o] = Wr[i];
    }
}

// ---------------- fused SAGE layer: gather-mean + dual GEMM + bias + relu ----------------

// VGPR=56 at this shape -> fits the 64-reg cap of 8 waves/EU; LDS 16KB * 8
// blocks = 128KB <= 160KB, so 8 blocks/CU resident for latency hiding.
__launch_bounds__(256, 8)
__global__ void sage_layer(const float* __restrict__ xin, float* __restrict__ xout,
                           const int* __restrict__ row_start, const int* __restrict__ csr,
                           const float* __restrict__ inv_deg,
                           const float* __restrict__ Wlt, const float* __restrict__ Wrt,
                           const float* __restrict__ bl, int n_nodes) {
    __shared__ __align__(16) float A[TM][D];
    __shared__ __align__(16) float X[TM][D];
    int block0 = blockIdx.x * TM;
    int tid = threadIdx.x;

    // Phase A: one wave per node (4 nodes/wave sequentially). Each wave splits
    // into two 32-lane halves; each half covers the full row (float4/lane) and
    // walks alternate edges with 4 accumulators -> 8 row loads in flight/wave.
    {
        int lane = tid & 63;
        int w    = tid >> 6;      // wave 0..3
        int h    = lane >> 5;     // half 0/1
        int sl   = lane & 31;     // sub-lane within half
        const char* xbase = (const char*)xin;
        int laneoff = sl * 16;

        for (int t = 0; t < 4; ++t) {
            int j = w * 4 + t;
            int n = block0 + j;
            float4 s0 = {0,0,0,0}, s1 = {0,0,0,0}, s2 = {0,0,0,0}, s3 = {0,0,0,0};
            float idg = 1.f;
            float2 xv = {0.f, 0.f};
            int e0 = 0, e1 = 0;
            if (n < n_nodes) {
                e0 = row_start[n];
                e1 = row_start[n + 1];
                idg = inv_deg[n];
                xv = ((const float2*)(xin + (size_t)n * D))[lane];
            }
            ((float2*)X[j])[lane] = xv;

            int e = e0 + h;
            for (; e + 6 < e1; e += 8) {
                int o0i = csr[e], o1i = csr[e + 2], o2i = csr[e + 4], o3i = csr[e + 6];
                float4 v0 = *(const float4*)(xbase + (size_t)(o0i + laneoff));
                float4 v1 = *(const float4*)(xbase + (size_t)(o1i + laneoff));
                float4 v2 = *(const float4*)(xbase + (size_t)(o2i + laneoff));
                float4 v3 = *(const float4*)(xbase + (size_t)(o3i + laneoff));
                s0.x += v0.x; s0.y += v0.y; s0.z += v0.z; s0.w += v0.w;
                s1.x += v1.x; s1.y += v1.y; s1.z += v1.z; s1.w += v1.w;
                s2.x += v2.x; s2.y += v2.y; s2.z += v2.z; s2.w += v2.w;
                s3.x += v3.x; s3.y += v3.y; s3.z += v3.z; s3.w += v3.w;
            }
            for (; e < e1; e += 2) {
                int o0i = csr[e];
                float4 v0 = *(const float4*)(xbase + (size_t)(o0i + laneoff));
                s0.x += v0.x; s0.y += v0.y; s0.z += v0.z; s0.w += v0.w;
            }

            float4 s;
            s.x = (s0.x + s1.x) + (s2.x + s3.x);
            s.y = (s0.y + s1.y) + (s2.y + s3.y);
            s.z = (s0.z + s1.z) + (s2.z + s3.z);
            s.w = (s0.w + s1.w) + (s2.w + s3.w);
            s.x += __shfl_down(s.x, 32);
            s.y += __shfl_down(s.y, 32);
            s.z += __shfl_down(s.z, 32);
            s.w += __shfl_down(s.w, 32);
            if (h == 0) {
                float4 r;
                r.x = s.x * idg; r.y = s.y * idg; r.z = s.z * idg; r.w = s.w * idg;
                ((float4*)A[j])[sl] = r;
            }
        }
    }
    __syncthreads();

    // Phase B: thread tile = 2 nodes x 4 features.
    int tf = tid & 31;        // feature group: f0 = tf*4
    int tn = tid >> 5;        // 0..7
    int j0 = tn * 2;
    const float4* Wlt4 = (const float4*)Wlt;
    const float4* Wrt4 = (const float4*)Wrt;
    float4 bv = ((const float4*)bl)[tf];
    float4 o0 = bv, o1 = bv;
    const float4* A0 = (const float4*)A[j0];
    const float4* A1 = (const float4*)A[j0 + 1];
    const float4* X0 = (const float4*)X[j0];
    const float4* X1 = (const float4*)X[j0 + 1];

    #pragma unroll 4
    for (int kk = 0; kk < 32; ++kk) {
        float4 a0 = A0[kk], a1 = A1[kk], x0 = X0[kk], x1 = X1[kk];
        #pragma unroll
        for (int c = 0; c < 4; ++c) {
            int k = kk * 4 + c;
            float4 wl = Wlt4[k * 32 + tf];
            float4 wr = Wrt4[k * 32 + tf];
            float ac0 = (&a0.x)[c], ac1 = (&a1.x)[c];
            float xc0 = (&x0.x)[c], xc1 = (&x1.x)[c];
            o0.x += wl.x * ac0 + wr.x * xc0;
            o0.y += wl.y * ac0 + wr.y * xc0;
            o0.z += wl.z * ac0 + wr.z * xc0;
            o0.w += wl.w * ac0 + wr.w * xc0;
            o1.x += wl.x * ac1 + wr.x * xc1;
            o1.y += wl.y * ac1 + wr.y * xc1;
            o1.z += wl.z * ac1 + wr.z * xc1;
            o1.w += wl.w * ac1 + wr.w * xc1;
        }
    }

    int n0 = block0 + j0, n1 = n0 + 1;
    if (n0 < n_nodes) {
        float4 r;
        r.x = fmaxf(o0.x, 0.f); r.y = fmaxf(o0.y, 0.f);
        r.z = fmaxf(o0.z, 0.f); r.w = fmaxf(o0.w, 0.f);
        ((float4*)xout)[(size_t)n0 * 32 + tf] = r;
    }
    if (n1 < n_nodes) {
        float4 r;
        r.x = fmaxf(o1.x, 0.f); r.y = fmaxf(o1.y, 0.f);
        r.z = fmaxf(o1.z, 0.f); r.w = fmaxf(o1.w, 0.f);
        ((float4*)xout)[(size_t)n1 * 32 + tf] = r;
    }
}

extern "C" void kernel_launch(void* const* d_in, const int* in_sizes, int n_in,
                              void* d_out, int out_size, void* d_ws, size_t ws_size,
                              hipStream_t stream) {
    const float* x  = (const float*)d_in[0];
    const int*  edge = (const int*)d_in[1];
    const float* Wl = (const float*)d_in[2];
    const float* bl = (const float*)d_in[3];
    const float* Wr = (const float*)d_in[4];

    int N = in_sizes[0] / D;
    int E = in_sizes[1] / 2;
    int L = in_sizes[3] / D;
    const int* srcp = edge;
    const int* dstp = edge + E;

    char* w = (char*)d_ws;
    auto alloc = [&](size_t bytes) {
        char* p = w;
        w += (bytes + 255) & ~(size_t)255;
        return p;
    };
    int*   deg       = (int*)alloc((size_t)N * 4);
    int*   local_ex  = (int*)alloc((size_t)N * 4);
    int*   row_start = (int*)alloc((size_t)(N + 1) * 4);
    int*   cursor    = (int*)alloc((size_t)N * 4);
    int*   csr       = (int*)alloc((size_t)E * 4);
    float* invdeg    = (float*)alloc((size_t)N * 4);
    int*   blocksum  = (int*)alloc((size_t)1024 * 4);
    float* wlt       = (float*)alloc((size_t)L * D * D * 4);
    float* wrt       = (float*)alloc((size_t)L * D * D * 4);
    float* buf0      = (float*)alloc((size_t)N * D * 4);

    int nb1 = (N + 1023) / 1024;
    hipMemsetAsync(deg, 0, (size_t)N * 4, stream);
    hist_kernel<<<(E + 255) / 256, 256, 0, stream>>>(dstp, deg, E);
    scan1_kernel<<<nb1, 1024, 0, stream>>>(deg, local_ex, blocksum, N);
    scan2_kernel<<<1, 1024, 0, stream>>>(blocksum, nb1);
    scan3_kernel<<<nb1, 1024, 0, stream>>>(deg, local_ex, blocksum, row_start,
                                           cursor, invdeg, N, E);
    scatter_kernel<<<(E + 255) / 256, 256, 0, stream>>>(srcp, dstp, cursor, csr, E);
    int tw = L * D * D;
    transpose_w<<<(tw + 255) / 256, 256, 0, stream>>>(Wl, Wr, wlt, wrt, tw);

    float* out = (float*)d_out;
    const float* cur = x;
    int nbl = (N + TM - 1) / TM;
    for (int l = 0; l < L; ++l) {
        float* o = (l & 1) ? out : buf0;
        if (l == L - 1) o = out;
        sage_layer<<<nbl, 256, 0, stream>>>(cur, o, row_start, csr, invdeg,
                                            wlt + (size_t)l * D * D,
                                            wrt + (size_t)l * D * D,
                                            bl + (size_t)l * D, N);
        cur = o;
    }
}

// Round 4
// 2816.935 us; speedup vs baseline: 1.9373x; 1.9373x over previous
//
#include <hip/hip_runtime.h>

#define D 128
#define TM 16

// ---------------- CSR build ----------------

__global__ void hist_kernel(const int* __restrict__ dst, int* __restrict__ deg, int E) {
    int i = blockIdx.x * blockDim.x + threadIdx.x;
    if (i < E) atomicAdd(&deg[dst[i]], 1);
}

__global__ void scan1_kernel(const int* __restrict__ deg, int* __restrict__ local_excl,
                             int* __restrict__ blocksum, int n) {
    __shared__ int tmp[1024];
    int i = blockIdx.x * 1024 + threadIdx.x;
    int v = (i < n) ? deg[i] : 0;
    tmp[threadIdx.x] = v;
    __syncthreads();
    for (int off = 1; off < 1024; off <<= 1) {
        int t = 0;
        if (threadIdx.x >= off) t = tmp[threadIdx.x - off];
        __syncthreads();
        if (threadIdx.x >= off) tmp[threadIdx.x] += t;
        __syncthreads();
    }
    int incl = tmp[threadIdx.x];
    if (i < n) local_excl[i] = incl - v;
    if (threadIdx.x == 1023) blocksum[blockIdx.x] = tmp[1023];
}

__global__ void scan2_kernel(int* __restrict__ blocksum, int nb) {
    __shared__ int tmp[1024];
    int v = (threadIdx.x < nb) ? blocksum[threadIdx.x] : 0;
    tmp[threadIdx.x] = v;
    __syncthreads();
    for (int off = 1; off < 1024; off <<= 1) {
        int t = 0;
        if (threadIdx.x >= off) t = tmp[threadIdx.x - off];
        __syncthreads();
        if (threadIdx.x >= off) tmp[threadIdx.x] += t;
        __syncthreads();
    }
    if (threadIdx.x < nb) blocksum[threadIdx.x] = tmp[threadIdx.x] - v;  // exclusive
}

__global__ void scan3_kernel(const int* __restrict__ deg, const int* __restrict__ local_excl,
                             const int* __restrict__ blocksum, int* __restrict__ row_start,
                             int* __restrict__ cursor, float* __restrict__ inv_deg,
                             int n, int n_edges) {
    int i = blockIdx.x * 1024 + threadIdx.x;
    if (i < n) {
        int rs = local_excl[i] + blocksum[blockIdx.x];
        row_start[i] = rs;
        cursor[i]    = rs;
        inv_deg[i]   = 1.0f / fmaxf((float)deg[i], 1.0f);
    }
    if (i == 0) row_start[n] = n_edges;
}

// csr[] holds BYTE offsets of the source row (src * D * 4).
__global__ void scatter_kernel(const int* __restrict__ src, const int* __restrict__ dst,
                               int* __restrict__ cursor, int* __restrict__ csr, int E) {
    int i = blockIdx.x * blockDim.x + threadIdx.x;
    if (i < E) {
        int d = dst[i];
        int p = atomicAdd(&cursor[d], 1);
        csr[p] = src[i] << 9;   // * 512 bytes per row
    }
}

// ---------------- weight transpose (W[l][f][k] -> Wt[l][k][f]) ----------------

__global__ void transpose_w(const float* __restrict__ Wl, const float* __restrict__ Wr,
                            float* __restrict__ Wlt, float* __restrict__ Wrt, int total) {
    int i = blockIdx.x * blockDim.x + threadIdx.x;
    if (i < total) {
        int l = i >> 14;
        int r = i & 16383;
        int f = r >> 7;
        int k = r & 127;
        int o = (l << 14) + (k << 7) + f;
        Wlt[o] = Wl[i];
        Wrt[o] = Wr[i];
    }
}

// ---------------- fused SAGE layer: gather-mean + dual GEMM + bias + relu ----------------

// (256,6): 6 blocks/CU = 24 waves/CU; VGPR cap 512/6 ~ 84 >= the ~56 this
// kernel needs, so no spill (round-3 lesson: (256,8) forced VGPR=32 and
// spilled 5.9 GB to scratch). LDS 6*16KB = 96KB <= 160KB.
__launch_bounds__(256, 6)
__global__ void sage_layer(const float* __restrict__ xin, float* __restrict__ xout,
                           const int* __restrict__ row_start, const int* __restrict__ csr,
                           const float* __restrict__ inv_deg,
                           const float* __restrict__ Wlt, const float* __restrict__ Wrt,
                           const float* __restrict__ bl, int n_nodes) {
    __shared__ __align__(16) float A[TM][D];
    __shared__ __align__(16) float X[TM][D];
    int block0 = blockIdx.x * TM;
    int tid = threadIdx.x;

    // Phase A: one wave per node (4 nodes/wave sequentially). Each wave splits
    // into two 32-lane halves; each half covers the full row (float4/lane) and
    // walks alternate edges with 4 accumulators -> 8 row loads in flight/wave.
    {
        int lane = tid & 63;
        int w    = tid >> 6;      // wave 0..3
        int h    = lane >> 5;     // half 0/1
        int sl   = lane & 31;     // sub-lane within half
        const char* xbase = (const char*)xin;
        int laneoff = sl * 16;

        for (int t = 0; t < 4; ++t) {
            int j = w * 4 + t;
            int n = block0 + j;
            float4 s0 = {0,0,0,0}, s1 = {0,0,0,0}, s2 = {0,0,0,0}, s3 = {0,0,0,0};
            float idg = 1.f;
            float2 xv = {0.f, 0.f};
            int e0 = 0, e1 = 0;
            if (n < n_nodes) {
                e0 = row_start[n];
                e1 = row_start[n + 1];
                idg = inv_deg[n];
                xv = ((const float2*)(xin + (size_t)n * D))[lane];
            }
            ((float2*)X[j])[lane] = xv;

            int e = e0 + h;
            for (; e + 6 < e1; e += 8) {
                int o0i = csr[e], o1i = csr[e + 2], o2i = csr[e + 4], o3i = csr[e + 6];
                float4 v0 = *(const float4*)(xbase + (size_t)(o0i + laneoff));
                float4 v1 = *(const float4*)(xbase + (size_t)(o1i + laneoff));
                float4 v2 = *(const float4*)(xbase + (size_t)(o2i + laneoff));
                float4 v3 = *(const float4*)(xbase + (size_t)(o3i + laneoff));
                s0.x += v0.x; s0.y += v0.y; s0.z += v0.z; s0.w += v0.w;
                s1.x += v1.x; s1.y += v1.y; s1.z += v1.z; s1.w += v1.w;
                s2.x += v2.x; s2.y += v2.y; s2.z += v2.z; s2.w += v2.w;
                s3.x += v3.x; s3.y += v3.y; s3.z += v3.z; s3.w += v3.w;
            }
            for (; e < e1; e += 2) {
                int o0i = csr[e];
                float4 v0 = *(const float4*)(xbase + (size_t)(o0i + laneoff));
                s0.x += v0.x; s0.y += v0.y; s0.z += v0.z; s0.w += v0.w;
            }

            float4 s;
            s.x = (s0.x + s1.x) + (s2.x + s3.x);
            s.y = (s0.y + s1.y) + (s2.y + s3.y);
            s.z = (s0.z + s1.z) + (s2.z + s3.z);
            s.w = (s0.w + s1.w) + (s2.w + s3.w);
            s.x += __shfl_down(s.x, 32);
            s.y += __shfl_down(s.y, 32);
            s.z += __shfl_down(s.z, 32);
            s.w += __shfl_down(s.w, 32);
            if (h == 0) {
                float4 r;
                r.x = s.x * idg; r.y = s.y * idg; r.z = s.z * idg; r.w = s.w * idg;
                ((float4*)A[j])[sl] = r;
            }
        }
    }
    __syncthreads();

    // Phase B: thread tile = 2 nodes x 4 features.
    int tf = tid & 31;        // feature group: f0 = tf*4
    int tn = tid >> 5;        // 0..7
    int j0 = tn * 2;
    const float4* Wlt4 = (const float4*)Wlt;
    const float4* Wrt4 = (const float4*)Wrt;
    float4 bv = ((const float4*)bl)[tf];
    float4 o0 = bv, o1 = bv;
    const float4* A0 = (const float4*)A[j0];
    const float4* A1 = (const float4*)A[j0 + 1];
    const float4* X0 = (const float4*)X[j0];
    const float4* X1 = (const float4*)X[j0 + 1];

    #pragma unroll 4
    for (int kk = 0; kk < 32; ++kk) {
        float4 a0 = A0[kk], a1 = A1[kk], x0 = X0[kk], x1 = X1[kk];
        #pragma unroll
        for (int c = 0; c < 4; ++c) {
            int k = kk * 4 + c;
            float4 wl = Wlt4[k * 32 + tf];
            float4 wr = Wrt4[k * 32 + tf];
            float ac0 = (&a0.x)[c], ac1 = (&a1.x)[c];
            float xc0 = (&x0.x)[c], xc1 = (&x1.x)[c];
            o0.x += wl.x * ac0 + wr.x * xc0;
            o0.y += wl.y * ac0 + wr.y * xc0;
            o0.z += wl.z * ac0 + wr.z * xc0;
            o0.w += wl.w * ac0 + wr.w * xc0;
            o1.x += wl.x * ac1 + wr.x * xc1;
            o1.y += wl.y * ac1 + wr.y * xc1;
            o1.z += wl.z * ac1 + wr.z * xc1;
            o1.w += wl.w * ac1 + wr.w * xc1;
        }
    }

    int n0 = block0 + j0, n1 = n0 + 1;
    if (n0 < n_nodes) {
        float4 r;
        r.x = fmaxf(o0.x, 0.f); r.y = fmaxf(o0.y, 0.f);
        r.z = fmaxf(o0.z, 0.f); r.w = fmaxf(o0.w, 0.f);
        ((float4*)xout)[(size_t)n0 * 32 + tf] = r;
    }
    if (n1 < n_nodes) {
        float4 r;
        r.x = fmaxf(o1.x, 0.f); r.y = fmaxf(o1.y, 0.f);
        r.z = fmaxf(o1.z, 0.f); r.w = fmaxf(o1.w, 0.f);
        ((float4*)xout)[(size_t)n1 * 32 + tf] = r;
    }
}

extern "C" void kernel_launch(void* const* d_in, const int* in_sizes, int n_in,
                              void* d_out, int out_size, void* d_ws, size_t ws_size,
                              hipStream_t stream) {
    const float* x  = (const float*)d_in[0];
    const int*  edge = (const int*)d_in[1];
    const float* Wl = (const float*)d_in[2];
    const float* bl = (const float*)d_in[3];
    const float* Wr = (const float*)d_in[4];

    int N = in_sizes[0] / D;
    int E = in_sizes[1] / 2;
    int L = in_sizes[3] / D;
    const int* srcp = edge;
    const int* dstp = edge + E;

    char* w = (char*)d_ws;
    auto alloc = [&](size_t bytes) {
        char* p = w;
        w += (bytes + 255) & ~(size_t)255;
        return p;
    };
    int*   deg       = (int*)alloc((size_t)N * 4);
    int*   local_ex  = (int*)alloc((size_t)N * 4);
    int*   row_start = (int*)alloc((size_t)(N + 1) * 4);
    int*   cursor    = (int*)alloc((size_t)N * 4);
    int*   csr       = (int*)alloc((size_t)E * 4);
    float* invdeg    = (float*)alloc((size_t)N * 4);
    int*   blocksum  = (int*)alloc((size_t)1024 * 4);
    float* wlt       = (float*)alloc((size_t)L * D * D * 4);
    float* wrt       = (float*)alloc((size_t)L * D * D * 4);
    float* buf0      = (float*)alloc((size_t)N * D * 4);

    int nb1 = (N + 1023) / 1024;
    hipMemsetAsync(deg, 0, (size_t)N * 4, stream);
    hist_kernel<<<(E + 255) / 256, 256, 0, stream>>>(dstp, deg, E);
    scan1_kernel<<<nb1, 1024, 0, stream>>>(deg, local_ex, blocksum, N);
    scan2_kernel<<<1, 1024, 0, stream>>>(blocksum, nb1);
    scan3_kernel<<<nb1, 1024, 0, stream>>>(deg, local_ex, blocksum, row_start,
                                           cursor, invdeg, N, E);
    scatter_kernel<<<(E + 255) / 256, 256, 0, stream>>>(srcp, dstp, cursor, csr, E);
    int tw = L * D * D;
    transpose_w<<<(tw + 255) / 256, 256, 0, stream>>>(Wl, Wr, wlt, wrt, tw);

    float* out = (float*)d_out;
    const float* cur = x;
    int nbl = (N + TM - 1) / TM;
    for (int l = 0; l < L; ++l) {
        float* o = (l & 1) ? out : buf0;
        if (l == L - 1) o = out;
        sage_layer<<<nbl, 256, 0, stream>>>(cur, o, row_start, csr, invdeg,
                                            wlt + (size_t)l * D * D,
                                            wrt + (size_t)l * D * D,
                                            bl + (size_t)l * D, N);
        cur = o;
    }
}

// Round 5
// 1521.944 us; speedup vs baseline: 3.5857x; 1.8509x over previous
//
#include <hip/hip_runtime.h>

#define D 128
#define TM 16
#define TN 64

// ---------------- CSR build ----------------

__global__ void hist_kernel(const int* __restrict__ dst, int* __restrict__ deg, int E) {
    int i = blockIdx.x * blockDim.x + threadIdx.x;
    if (i < E) atomicAdd(&deg[dst[i]], 1);
}

__global__ void scan1_kernel(const int* __restrict__ deg, int* __restrict__ local_excl,
                             int* __restrict__ blocksum, int n) {
    __shared__ int tmp[1024];
    int i = blockIdx.x * 1024 + threadIdx.x;
    int v = (i < n) ? deg[i] : 0;
    tmp[threadIdx.x] = v;
    __syncthreads();
    for (int off = 1; off < 1024; off <<= 1) {
        int t = 0;
        if (threadIdx.x >= off) t = tmp[threadIdx.x - off];
        __syncthreads();
        if (threadIdx.x >= off) tmp[threadIdx.x] += t;
        __syncthreads();
    }
    int incl = tmp[threadIdx.x];
    if (i < n) local_excl[i] = incl - v;
    if (threadIdx.x == 1023) blocksum[blockIdx.x] = tmp[1023];
}

__global__ void scan2_kernel(int* __restrict__ blocksum, int nb) {
    __shared__ int tmp[1024];
    int v = (threadIdx.x < nb) ? blocksum[threadIdx.x] : 0;
    tmp[threadIdx.x] = v;
    __syncthreads();
    for (int off = 1; off < 1024; off <<= 1) {
        int t = 0;
        if (threadIdx.x >= off) t = tmp[threadIdx.x - off];
        __syncthreads();
        if (threadIdx.x >= off) tmp[threadIdx.x] += t;
        __syncthreads();
    }
    if (threadIdx.x < nb) blocksum[threadIdx.x] = tmp[threadIdx.x] - v;  // exclusive
}

__global__ void scan3_kernel(const int* __restrict__ deg, const int* __restrict__ local_excl,
                             const int* __restrict__ blocksum, int* __restrict__ row_start,
                             int* __restrict__ cursor, float* __restrict__ inv_deg,
                             int n, int n_edges) {
    int i = blockIdx.x * 1024 + threadIdx.x;
    if (i < n) {
        int rs = local_excl[i] + blocksum[blockIdx.x];
        row_start[i] = rs;
        cursor[i]    = rs;
        inv_deg[i]   = 1.0f / fmaxf((float)deg[i], 1.0f);
    }
    if (i == 0) row_start[n] = n_edges;
}

// csr[] holds BYTE offsets of the source row (src * D * 4).
__global__ void scatter_kernel(const int* __restrict__ src, const int* __restrict__ dst,
                               int* __restrict__ cursor, int* __restrict__ csr, int E) {
    int i = blockIdx.x * blockDim.x + threadIdx.x;
    if (i < E) {
        int d = dst[i];
        int p = atomicAdd(&cursor[d], 1);
        csr[p] = src[i] << 9;   // * 512 bytes per row
    }
}

// ---------------- weight transpose (W[l][f][k] -> Wt[l][k][f]) ----------------

__global__ void transpose_w(const float* __restrict__ Wl, const float* __restrict__ Wr,
                            float* __restrict__ Wlt, float* __restrict__ Wrt, int total) {
    int i = blockIdx.x * blockDim.x + threadIdx.x;
    if (i < total) {
        int l = i >> 14;
        int r = i & 16383;
        int f = r >> 7;
        int k = r & 127;
        int o = (l << 14) + (k << 7) + f;
        Wlt[o] = Wl[i];
        Wrt[o] = Wr[i];
    }
}

// ---------------- gather-mean kernel (no LDS) ----------------
// One wave per node (4 nodes/wave sequential). Wave splits into two 32-lane
// halves walking alternate edges, 4-deep float4 pipeline per half = 8 row
// loads in flight/wave. VGPR ~56 -> ~4 waves/SIMD (empirical cap 256/VGPR;
// >4 waves/EU spills -- round 3/4 lesson).
__global__ void agg_kernel(const float* __restrict__ xin, float* __restrict__ agg,
                           const int* __restrict__ row_start, const int* __restrict__ csr,
                           const float* __restrict__ inv_deg, int n_nodes) {
    int tid  = threadIdx.x;
    int lane = tid & 63;
    int w    = tid >> 6;      // wave 0..3
    int h    = lane >> 5;     // half 0/1
    int sl   = lane & 31;
    const char* xbase = (const char*)xin;
    int laneoff = sl * 16;
    int block0 = blockIdx.x * TM;

    for (int t = 0; t < 4; ++t) {
        int n = block0 + w * 4 + t;
        if (n >= n_nodes) return;
        int e0 = row_start[n];
        int e1 = row_start[n + 1];
        float idg = inv_deg[n];
        float4 s0 = {0,0,0,0}, s1 = {0,0,0,0}, s2 = {0,0,0,0}, s3 = {0,0,0,0};

        int e = e0 + h;
        for (; e + 6 < e1; e += 8) {
            int o0i = csr[e], o1i = csr[e + 2], o2i = csr[e + 4], o3i = csr[e + 6];
            float4 v0 = *(const float4*)(xbase + (size_t)(o0i + laneoff));
            float4 v1 = *(const float4*)(xbase + (size_t)(o1i + laneoff));
            float4 v2 = *(const float4*)(xbase + (size_t)(o2i + laneoff));
            float4 v3 = *(const float4*)(xbase + (size_t)(o3i + laneoff));
            s0.x += v0.x; s0.y += v0.y; s0.z += v0.z; s0.w += v0.w;
            s1.x += v1.x; s1.y += v1.y; s1.z += v1.z; s1.w += v1.w;
            s2.x += v2.x; s2.y += v2.y; s2.z += v2.z; s2.w += v2.w;
            s3.x += v3.x; s3.y += v3.y; s3.z += v3.z; s3.w += v3.w;
        }
        for (; e < e1; e += 2) {
            int o0i = csr[e];
            float4 v0 = *(const float4*)(xbase + (size_t)(o0i + laneoff));
            s0.x += v0.x; s0.y += v0.y; s0.z += v0.z; s0.w += v0.w;
        }

        float4 s;
        s.x = (s0.x + s1.x) + (s2.x + s3.x);
        s.y = (s0.y + s1.y) + (s2.y + s3.y);
        s.z = (s0.z + s1.z) + (s2.z + s3.z);
        s.w = (s0.w + s1.w) + (s2.w + s3.w);
        s.x += __shfl_down(s.x, 32);
        s.y += __shfl_down(s.y, 32);
        s.z += __shfl_down(s.z, 32);
        s.w += __shfl_down(s.w, 32);
        if (h == 0) {
            float4 r;
            r.x = s.x * idg; r.y = s.y * idg; r.z = s.z * idg; r.w = s.w * idg;
            ((float4*)(agg + (size_t)n * D))[sl] = r;
        }
    }
}

// ---------------- dual-GEMM + bias + relu kernel ----------------
// 64-node tile, thread = 8 nodes x 4 features => each weight float4 loaded
// feeds 64 FMAs (4x the reuse of the old fused kernel). A/X in 64KB LDS;
// per-wave ds_read hits 2 distinct addresses (broadcast, free).
__launch_bounds__(256)
__global__ void gemm_kernel(const float* __restrict__ agg, const float* __restrict__ xin,
                            float* __restrict__ xout,
                            const float* __restrict__ Wlt, const float* __restrict__ Wrt,
                            const float* __restrict__ bl, int n_nodes) {
    __shared__ __align__(16) float A[TN][D];
    __shared__ __align__(16) float X[TN][D];
    int tid = threadIdx.x;
    int block0 = blockIdx.x * TN;

    // stage 64 rows of agg and x (2048 float4 each)
    const float4* agg4 = (const float4*)(agg + (size_t)block0 * D);
    const float4* x4   = (const float4*)(xin + (size_t)block0 * D);
    float4* A4 = (float4*)A;
    float4* X4 = (float4*)X;
    int limit4 = (n_nodes - block0) * 32;   // float4s available in this tile
    #pragma unroll
    for (int t = 0; t < 8; ++t) {
        int i = t * 256 + tid;
        float4 za = {0,0,0,0}, zx = {0,0,0,0};
        if (i < limit4) { za = agg4[i]; zx = x4[i]; }
        A4[i] = za;
        X4[i] = zx;
    }
    __syncthreads();

    int tf = tid & 31;      // feature float4 index
    int tn = tid >> 5;      // node group 0..7 -> nodes tn*8..tn*8+7
    const float4* Wlt4 = (const float4*)Wlt;
    const float4* Wrt4 = (const float4*)Wrt;
    float4 bv = ((const float4*)bl)[tf];
    float4 acc[8];
    #pragma unroll
    for (int i = 0; i < 8; ++i) acc[i] = bv;

    int nbase = tn * 8;
    #pragma unroll 4
    for (int k = 0; k < D; k += 2) {
        float4 wl0 = Wlt4[k * 32 + tf];
        float4 wr0 = Wrt4[k * 32 + tf];
        float4 wl1 = Wlt4[(k + 1) * 32 + tf];
        float4 wr1 = Wrt4[(k + 1) * 32 + tf];
        #pragma unroll
        for (int i = 0; i < 8; ++i) {
            float2 a  = *(const float2*)&A[nbase + i][k];
            float2 xx = *(const float2*)&X[nbase + i][k];
            acc[i].x += wl0.x * a.x + wr0.x * xx.x + wl1.x * a.y + wr1.x * xx.y;
            acc[i].y += wl0.y * a.x + wr0.y * xx.x + wl1.y * a.y + wr1.y * xx.y;
            acc[i].z += wl0.z * a.x + wr0.z * xx.x + wl1.z * a.y + wr1.z * xx.y;
            acc[i].w += wl0.w * a.x + wr0.w * xx.x + wl1.w * a.y + wr1.w * xx.y;
        }
    }

    #pragma unroll
    for (int i = 0; i < 8; ++i) {
        int n = block0 + nbase + i;
        if (n < n_nodes) {
            float4 r;
            r.x = fmaxf(acc[i].x, 0.f);
            r.y = fmaxf(acc[i].y, 0.f);
            r.z = fmaxf(acc[i].z, 0.f);
            r.w = fmaxf(acc[i].w, 0.f);
            ((float4*)xout)[(size_t)n * 32 + tf] = r;
        }
    }
}

extern "C" void kernel_launch(void* const* d_in, const int* in_sizes, int n_in,
                              void* d_out, int out_size, void* d_ws, size_t ws_size,
                              hipStream_t stream) {
    const float* x  = (const float*)d_in[0];
    const int*  edge = (const int*)d_in[1];
    const float* Wl = (const float*)d_in[2];
    const float* bl = (const float*)d_in[3];
    const float* Wr = (const float*)d_in[4];

    int N = in_sizes[0] / D;
    int E = in_sizes[1] / 2;
    int L = in_sizes[3] / D;
    const int* srcp = edge;
    const int* dstp = edge + E;

    char* w = (char*)d_ws;
    auto alloc = [&](size_t bytes) {
        char* p = w;
        w += (bytes + 255) & ~(size_t)255;
        return p;
    };
    int*   deg       = (int*)alloc((size_t)N * 4);
    int*   local_ex  = (int*)alloc((size_t)N * 4);
    int*   row_start = (int*)alloc((size_t)(N + 1) * 4);
    int*   cursor    = (int*)alloc((size_t)N * 4);
    int*   csr       = (int*)alloc((size_t)E * 4);
    float* invdeg    = (float*)alloc((size_t)N * 4);
    int*   blocksum  = (int*)alloc((size_t)1024 * 4);
    float* wlt       = (float*)alloc((size_t)L * D * D * 4);
    float* wrt       = (float*)alloc((size_t)L * D * D * 4);
    float* buf0      = (float*)alloc((size_t)N * D * 4);
    float* aggbuf    = (float*)alloc((size_t)N * D * 4);

    int nb1 = (N + 1023) / 1024;
    hipMemsetAsync(deg, 0, (size_t)N * 4, stream);
    hist_kernel<<<(E + 255) / 256, 256, 0, stream>>>(dstp, deg, E);
    scan1_kernel<<<nb1, 1024, 0, stream>>>(deg, local_ex, blocksum, N);
    scan2_kernel<<<1, 1024, 0, stream>>>(blocksum, nb1);
    scan3_kernel<<<nb1, 1024, 0, stream>>>(deg, local_ex, blocksum, row_start,
                                           cursor, invdeg, N, E);
    scatter_kernel<<<(E + 255) / 256, 256, 0, stream>>>(srcp, dstp, cursor, csr, E);
    int tw = L * D * D;
    transpose_w<<<(tw + 255) / 256, 256, 0, stream>>>(Wl, Wr, wlt, wrt, tw);

    float* out = (float*)d_out;
    const float* cur = x;
    int nb_agg  = (N + TM - 1) / TM;
    int nb_gemm = (N + TN - 1) / TN;
    for (int l = 0; l < L; ++l) {
        float* o = (l & 1) ? out : buf0;
        if (l == L - 1) o = out;
        agg_kernel<<<nb_agg, 256, 0, stream>>>(cur, aggbuf, row_start, csr, invdeg, N);
        gemm_kernel<<<nb_gemm, 256, 0, stream>>>(aggbuf, cur, o,
                                                 wlt + (size_t)l * D * D,
                                                 wrt + (size_t)l * D * D,
                                                 bl + (size_t)l * D, N);
        cur = o;
    }
}

// Round 6
// 1407.782 us; speedup vs baseline: 3.8765x; 1.0811x over previous
//
#include <hip/hip_runtime.h>

#define D 128
#define TM 16
#define TG 32   // gemm node tile (32 KB LDS total -> 5 blocks/CU)

// ---------------- CSR build ----------------

__global__ void hist_kernel(const int* __restrict__ dst, int* __restrict__ deg, int E) {
    int i = blockIdx.x * blockDim.x + threadIdx.x;
    if (i < E) atomicAdd(&deg[dst[i]], 1);
}

__global__ void scan1_kernel(const int* __restrict__ deg, int* __restrict__ local_excl,
                             int* __restrict__ blocksum, int n) {
    __shared__ int tmp[1024];
    int i = blockIdx.x * 1024 + threadIdx.x;
    int v = (i < n) ? deg[i] : 0;
    tmp[threadIdx.x] = v;
    __syncthreads();
    for (int off = 1; off < 1024; off <<= 1) {
        int t = 0;
        if (threadIdx.x >= off) t = tmp[threadIdx.x - off];
        __syncthreads();
        if (threadIdx.x >= off) tmp[threadIdx.x] += t;
        __syncthreads();
    }
    int incl = tmp[threadIdx.x];
    if (i < n) local_excl[i] = incl - v;
    if (threadIdx.x == 1023) blocksum[blockIdx.x] = tmp[1023];
}

__global__ void scan2_kernel(int* __restrict__ blocksum, int nb) {
    __shared__ int tmp[1024];
    int v = (threadIdx.x < nb) ? blocksum[threadIdx.x] : 0;
    tmp[threadIdx.x] = v;
    __syncthreads();
    for (int off = 1; off < 1024; off <<= 1) {
        int t = 0;
        if (threadIdx.x >= off) t = tmp[threadIdx.x - off];
        __syncthreads();
        if (threadIdx.x >= off) tmp[threadIdx.x] += t;
        __syncthreads();
    }
    if (threadIdx.x < nb) blocksum[threadIdx.x] = tmp[threadIdx.x] - v;  // exclusive
}

__global__ void scan3_kernel(const int* __restrict__ deg, const int* __restrict__ local_excl,
                             const int* __restrict__ blocksum, int* __restrict__ row_start,
                             int* __restrict__ cursor, float* __restrict__ inv_deg,
                             int n, int n_edges) {
    int i = blockIdx.x * 1024 + threadIdx.x;
    if (i < n) {
        int rs = local_excl[i] + blocksum[blockIdx.x];
        row_start[i] = rs;
        cursor[i]    = rs;
        inv_deg[i]   = 1.0f / fmaxf((float)deg[i], 1.0f);
    }
    if (i == 0) row_start[n] = n_edges;
}

// csr[] holds BYTE offsets of the source row (src * D * 4).
__global__ void scatter_kernel(const int* __restrict__ src, const int* __restrict__ dst,
                               int* __restrict__ cursor, int* __restrict__ csr, int E) {
    int i = blockIdx.x * blockDim.x + threadIdx.x;
    if (i < E) {
        int d = dst[i];
        int p = atomicAdd(&cursor[d], 1);
        csr[p] = src[i] << 9;   // * 512 bytes per row
    }
}

// ---------------- weight transpose (W[l][f][k] -> Wt[l][k][f]) ----------------

__global__ void transpose_w(const float* __restrict__ Wl, const float* __restrict__ Wr,
                            float* __restrict__ Wlt, float* __restrict__ Wrt, int total) {
    int i = blockIdx.x * blockDim.x + threadIdx.x;
    if (i < total) {
        int l = i >> 14;
        int r = i & 16383;
        int f = r >> 7;
        int k = r & 127;
        int o = (l << 14) + (k << 7) + f;
        Wlt[o] = Wl[i];
        Wrt[o] = Wr[i];
    }
}

// ---------------- gather-mean kernel (no LDS) ----------------
// One wave per node (4 nodes/wave sequential). Wave splits into two 32-lane
// halves walking alternate edges, 4-deep float4 pipeline per half = 8 row
// loads in flight/wave. VGPR ~56; no launch_bounds (r3/r4: min-waves bound
// forces VGPR squeeze + scratch spill).
__global__ void agg_kernel(const float* __restrict__ xin, float* __restrict__ agg,
                           const int* __restrict__ row_start, const int* __restrict__ csr,
                           const float* __restrict__ inv_deg, int n_nodes) {
    int tid  = threadIdx.x;
    int lane = tid & 63;
    int w    = tid >> 6;      // wave 0..3
    int h    = lane >> 5;     // half 0/1
    int sl   = lane & 31;
    const char* xbase = (const char*)xin;
    int laneoff = sl * 16;
    int block0 = blockIdx.x * TM;

    for (int t = 0; t < 4; ++t) {
        int n = block0 + w * 4 + t;
        if (n >= n_nodes) return;
        int e0 = row_start[n];
        int e1 = row_start[n + 1];
        float idg = inv_deg[n];
        float4 s0 = {0,0,0,0}, s1 = {0,0,0,0}, s2 = {0,0,0,0}, s3 = {0,0,0,0};

        int e = e0 + h;
        for (; e + 6 < e1; e += 8) {
            int o0i = csr[e], o1i = csr[e + 2], o2i = csr[e + 4], o3i = csr[e + 6];
            float4 v0 = *(const float4*)(xbase + (size_t)(o0i + laneoff));
            float4 v1 = *(const float4*)(xbase + (size_t)(o1i + laneoff));
            float4 v2 = *(const float4*)(xbase + (size_t)(o2i + laneoff));
            float4 v3 = *(const float4*)(xbase + (size_t)(o3i + laneoff));
            s0.x += v0.x; s0.y += v0.y; s0.z += v0.z; s0.w += v0.w;
            s1.x += v1.x; s1.y += v1.y; s1.z += v1.z; s1.w += v1.w;
            s2.x += v2.x; s2.y += v2.y; s2.z += v2.z; s2.w += v2.w;
            s3.x += v3.x; s3.y += v3.y; s3.z += v3.z; s3.w += v3.w;
        }
        for (; e < e1; e += 2) {
            int o0i = csr[e];
            float4 v0 = *(const float4*)(xbase + (size_t)(o0i + laneoff));
            s0.x += v0.x; s0.y += v0.y; s0.z += v0.z; s0.w += v0.w;
        }

        float4 s;
        s.x = (s0.x + s1.x) + (s2.x + s3.x);
        s.y = (s0.y + s1.y) + (s2.y + s3.y);
        s.z = (s0.z + s1.z) + (s2.z + s3.z);
        s.w = (s0.w + s1.w) + (s2.w + s3.w);
        s.x += __shfl_down(s.x, 32);
        s.y += __shfl_down(s.y, 32);
        s.z += __shfl_down(s.z, 32);
        s.w += __shfl_down(s.w, 32);
        if (h == 0) {
            float4 r;
            r.x = s.x * idg; r.y = s.y * idg; r.z = s.z * idg; r.w = s.w * idg;
            ((float4*)(agg + (size_t)n * D))[sl] = r;
        }
    }
}

// ---------------- dual-GEMM + bias + relu kernel ----------------
// 32-node tile (32 KB LDS -> 5 blocks/CU for latency hiding; r5's 64-node
// tile was 2 blocks/CU = 18% occupancy, latency-bound at 217 us).
// Thread = 4 nodes x 4 features; weight float4s stream from L2 (coalesced,
// perfectly reused within the wave); A/X broadcast-read from LDS.
__global__ void gemm_kernel(const float* __restrict__ agg, const float* __restrict__ xin,
                            float* __restrict__ xout,
                            const float* __restrict__ Wlt, const float* __restrict__ Wrt,
                            const float* __restrict__ bl, int n_nodes) {
    __shared__ __align__(16) float A[TG][D];
    __shared__ __align__(16) float X[TG][D];
    int tid = threadIdx.x;
    int block0 = blockIdx.x * TG;

    // stage 32 rows of agg and x (1024 float4 each -> 4 per thread each)
    const float4* agg4 = (const float4*)(agg + (size_t)block0 * D);
    const float4* x4   = (const float4*)(xin + (size_t)block0 * D);
    float4* A4 = (float4*)A;
    float4* X4 = (float4*)X;
    int limit4 = (n_nodes - block0) * 32;   // float4s available in this tile
    #pragma unroll
    for (int t = 0; t < 4; ++t) {
        int i = t * 256 + tid;
        float4 za = {0,0,0,0}, zx = {0,0,0,0};
        if (i < limit4) { za = agg4[i]; zx = x4[i]; }
        A4[i] = za;
        X4[i] = zx;
    }
    __syncthreads();

    int tf = tid & 31;      // feature float4 index
    int tn = tid >> 5;      // node group 0..7 -> nodes tn*4..tn*4+3
    const float4* Wlt4 = (const float4*)Wlt;
    const float4* Wrt4 = (const float4*)Wrt;
    float4 bv = ((const float4*)bl)[tf];
    float4 acc[4];
    #pragma unroll
    for (int i = 0; i < 4; ++i) acc[i] = bv;

    int nbase = tn * 4;
    #pragma unroll 4
    for (int k = 0; k < D; k += 2) {
        float4 wl0 = Wlt4[k * 32 + tf];
        float4 wr0 = Wrt4[k * 32 + tf];
        float4 wl1 = Wlt4[(k + 1) * 32 + tf];
        float4 wr1 = Wrt4[(k + 1) * 32 + tf];
        #pragma unroll
        for (int i = 0; i < 4; ++i) {
            float2 a  = *(const float2*)&A[nbase + i][k];
            float2 xx = *(const float2*)&X[nbase + i][k];
            acc[i].x += wl0.x * a.x + wr0.x * xx.x + wl1.x * a.y + wr1.x * xx.y;
            acc[i].y += wl0.y * a.x + wr0.y * xx.x + wl1.y * a.y + wr1.y * xx.y;
            acc[i].z += wl0.z * a.x + wr0.z * xx.x + wl1.z * a.y + wr1.z * xx.y;
            acc[i].w += wl0.w * a.x + wr0.w * xx.x + wl1.w * a.y + wr1.w * xx.y;
        }
    }

    #pragma unroll
    for (int i = 0; i < 4; ++i) {
        int n = block0 + nbase + i;
        if (n < n_nodes) {
            float4 r;
            r.x = fmaxf(acc[i].x, 0.f);
            r.y = fmaxf(acc[i].y, 0.f);
            r.z = fmaxf(acc[i].z, 0.f);
            r.w = fmaxf(acc[i].w, 0.f);
            ((float4*)xout)[(size_t)n * 32 + tf] = r;
        }
    }
}

extern "C" void kernel_launch(void* const* d_in, const int* in_sizes, int n_in,
                              void* d_out, int out_size, void* d_ws, size_t ws_size,
                              hipStream_t stream) {
    const float* x  = (const float*)d_in[0];
    const int*  edge = (const int*)d_in[1];
    const float* Wl = (const float*)d_in[2];
    const float* bl = (const float*)d_in[3];
    const float* Wr = (const float*)d_in[4];

    int N = in_sizes[0] / D;
    int E = in_sizes[1] / 2;
    int L = in_sizes[3] / D;
    const int* srcp = edge;
    const int* dstp = edge + E;

    char* w = (char*)d_ws;
    auto alloc = [&](size_t bytes) {
        char* p = w;
        w += (bytes + 255) & ~(size_t)255;
        return p;
    };
    int*   deg       = (int*)alloc((size_t)N * 4);
    int*   local_ex  = (int*)alloc((size_t)N * 4);
    int*   row_start = (int*)alloc((size_t)(N + 1) * 4);
    int*   cursor    = (int*)alloc((size_t)N * 4);
    int*   csr       = (int*)alloc((size_t)E * 4);
    float* invdeg    = (float*)alloc((size_t)N * 4);
    int*   blocksum  = (int*)alloc((size_t)1024 * 4);
    float* wlt       = (float*)alloc((size_t)L * D * D * 4);
    float* wrt       = (float*)alloc((size_t)L * D * D * 4);
    float* buf0      = (float*)alloc((size_t)N * D * 4);
    float* aggbuf    = (float*)alloc((size_t)N * D * 4);

    int nb1 = (N + 1023) / 1024;
    hipMemsetAsync(deg, 0, (size_t)N * 4, stream);
    hist_kernel<<<(E + 255) / 256, 256, 0, stream>>>(dstp, deg, E);
    scan1_kernel<<<nb1, 1024, 0, stream>>>(deg, local_ex, blocksum, N);
    scan2_kernel<<<1, 1024, 0, stream>>>(blocksum, nb1);
    scan3_kernel<<<nb1, 1024, 0, stream>>>(deg, local_ex, blocksum, row_start,
                                           cursor, invdeg, N, E);
    scatter_kernel<<<(E + 255) / 256, 256, 0, stream>>>(srcp, dstp, cursor, csr, E);
    int tw = L * D * D;
    transpose_w<<<(tw + 255) / 256, 256, 0, stream>>>(Wl, Wr, wlt, wrt, tw);

    float* out = (float*)d_out;
    const float* cur = x;
    int nb_agg  = (N + TM - 1) / TM;
    int nb_gemm = (N + TG - 1) / TG;
    for (int l = 0; l < L; ++l) {
        float* o = (l & 1) ? out : buf0;
        if (l == L - 1) o = out;
        agg_kernel<<<nb_agg, 256, 0, stream>>>(cur, aggbuf, row_start, csr, invdeg, N);
        gemm_kernel<<<nb_gemm, 256, 0, stream>>>(aggbuf, cur, o,
                                                 wlt + (size_t)l * D * D,
                                                 wrt + (size_t)l * D * D,
                                                 bl + (size_t)l * D, N);
        cur = o;
    }
}

// Round 7
// 1322.429 us; speedup vs baseline: 4.1267x; 1.0645x over previous
//
#include <hip/hip_runtime.h>

#define D 128
#define TM 16
#define TG 32   // gemm node tile (32 KB LDS total)

// ---------------- CSR build ----------------

__global__ void hist_kernel(const int* __restrict__ dst, int* __restrict__ deg, int E) {
    int i = blockIdx.x * blockDim.x + threadIdx.x;
    if (i < E) atomicAdd(&deg[dst[i]], 1);
}

__global__ void scan1_kernel(const int* __restrict__ deg, int* __restrict__ local_excl,
                             int* __restrict__ blocksum, int n) {
    __shared__ int tmp[1024];
    int i = blockIdx.x * 1024 + threadIdx.x;
    int v = (i < n) ? deg[i] : 0;
    tmp[threadIdx.x] = v;
    __syncthreads();
    for (int off = 1; off < 1024; off <<= 1) {
        int t = 0;
        if (threadIdx.x >= off) t = tmp[threadIdx.x - off];
        __syncthreads();
        if (threadIdx.x >= off) tmp[threadIdx.x] += t;
        __syncthreads();
    }
    int incl = tmp[threadIdx.x];
    if (i < n) local_excl[i] = incl - v;
    if (threadIdx.x == 1023) blocksum[blockIdx.x] = tmp[1023];
}

__global__ void scan2_kernel(int* __restrict__ blocksum, int nb) {
    __shared__ int tmp[1024];
    int v = (threadIdx.x < nb) ? blocksum[threadIdx.x] : 0;
    tmp[threadIdx.x] = v;
    __syncthreads();
    for (int off = 1; off < 1024; off <<= 1) {
        int t = 0;
        if (threadIdx.x >= off) t = tmp[threadIdx.x - off];
        __syncthreads();
        if (threadIdx.x >= off) tmp[threadIdx.x] += t;
        __syncthreads();
    }
    if (threadIdx.x < nb) blocksum[threadIdx.x] = tmp[threadIdx.x] - v;  // exclusive
}

__global__ void scan3_kernel(const int* __restrict__ deg, const int* __restrict__ local_excl,
                             const int* __restrict__ blocksum, int* __restrict__ row_start,
                             int* __restrict__ cursor, float* __restrict__ inv_deg,
                             int n, int n_edges) {
    int i = blockIdx.x * 1024 + threadIdx.x;
    if (i < n) {
        int rs = local_excl[i] + blocksum[blockIdx.x];
        row_start[i] = rs;
        cursor[i]    = rs;
        inv_deg[i]   = 1.0f / fmaxf((float)deg[i], 1.0f);
    }
    if (i == 0) row_start[n] = n_edges;
}

// csr[] holds BYTE offsets of the source row (src * D * 4).
__global__ void scatter_kernel(const int* __restrict__ src, const int* __restrict__ dst,
                               int* __restrict__ cursor, int* __restrict__ csr, int E) {
    int i = blockIdx.x * blockDim.x + threadIdx.x;
    if (i < E) {
        int d = dst[i];
        int p = atomicAdd(&cursor[d], 1);
        csr[p] = src[i] << 9;   // * 512 bytes per row
    }
}

// ---------------- weight transpose (W[l][f][k] -> Wt[l][k][f]) ----------------

__global__ void transpose_w(const float* __restrict__ Wl, const float* __restrict__ Wr,
                            float* __restrict__ Wlt, float* __restrict__ Wrt, int total) {
    int i = blockIdx.x * blockDim.x + threadIdx.x;
    if (i < total) {
        int l = i >> 14;
        int r = i & 16383;
        int f = r >> 7;
        int k = r & 127;
        int o = (l << 14) + (k << 7) + f;
        Wlt[o] = Wl[i];
        Wrt[o] = Wr[i];
    }
}

// ---------------- gather-mean kernel (no LDS) ----------------
// One wave per node (4 nodes/wave sequential). Wave splits into two 32-lane
// halves walking alternate edges, 4-deep float4 pipeline per half = 8 row
// loads in flight/wave. ~122 us/layer ~= L3 gather-BW floor (819 MB/layer).
__global__ void agg_kernel(const float* __restrict__ xin, float* __restrict__ agg,
                           const int* __restrict__ row_start, const int* __restrict__ csr,
                           const float* __restrict__ inv_deg, int n_nodes) {
    int tid  = threadIdx.x;
    int lane = tid & 63;
    int w    = tid >> 6;      // wave 0..3
    int h    = lane >> 5;     // half 0/1
    int sl   = lane & 31;
    const char* xbase = (const char*)xin;
    int laneoff = sl * 16;
    int block0 = blockIdx.x * TM;

    for (int t = 0; t < 4; ++t) {
        int n = block0 + w * 4 + t;
        if (n >= n_nodes) return;
        int e0 = row_start[n];
        int e1 = row_start[n + 1];
        float idg = inv_deg[n];
        float4 s0 = {0,0,0,0}, s1 = {0,0,0,0}, s2 = {0,0,0,0}, s3 = {0,0,0,0};

        int e = e0 + h;
        for (; e + 6 < e1; e += 8) {
            int o0i = csr[e], o1i = csr[e + 2], o2i = csr[e + 4], o3i = csr[e + 6];
            float4 v0 = *(const float4*)(xbase + (size_t)(o0i + laneoff));
            float4 v1 = *(const float4*)(xbase + (size_t)(o1i + laneoff));
            float4 v2 = *(const float4*)(xbase + (size_t)(o2i + laneoff));
            float4 v3 = *(const float4*)(xbase + (size_t)(o3i + laneoff));
            s0.x += v0.x; s0.y += v0.y; s0.z += v0.z; s0.w += v0.w;
            s1.x += v1.x; s1.y += v1.y; s1.z += v1.z; s1.w += v1.w;
            s2.x += v2.x; s2.y += v2.y; s2.z += v2.z; s2.w += v2.w;
            s3.x += v3.x; s3.y += v3.y; s3.z += v3.z; s3.w += v3.w;
        }
        for (; e < e1; e += 2) {
            int o0i = csr[e];
            float4 v0 = *(const float4*)(xbase + (size_t)(o0i + laneoff));
            s0.x += v0.x; s0.y += v0.y; s0.z += v0.z; s0.w += v0.w;
        }

        float4 s;
        s.x = (s0.x + s1.x) + (s2.x + s3.x);
        s.y = (s0.y + s1.y) + (s2.y + s3.y);
        s.z = (s0.z + s1.z) + (s2.z + s3.z);
        s.w = (s0.w + s1.w) + (s2.w + s3.w);
        s.x += __shfl_down(s.x, 32);
        s.y += __shfl_down(s.y, 32);
        s.z += __shfl_down(s.z, 32);
        s.w += __shfl_down(s.w, 32);
        if (h == 0) {
            float4 r;
            r.x = s.x * idg; r.y = s.y * idg; r.z = s.z * idg; r.w = s.w * idg;
            ((float4*)(agg + (size_t)n * D))[sl] = r;
        }
    }
}

// ---------------- dual-GEMM + bias + relu kernel ----------------
// 32-node tile. Thread = 4 nodes x 4 features. Inner product written as
// chained single-product `acc += w * v` statements so every op contracts to
// v_fmac_f32 (r6 lesson: the 4-product expression tree compiled to
// mul+add = 2x VALU instructions, capping at 34 TF). 16 independent
// accumulator chains give the ILP; A/X read as float4 (ds_read_b128,
// 2 distinct addrs/wave = free broadcast).
__global__ void gemm_kernel(const float* __restrict__ agg, const float* __restrict__ xin,
                            float* __restrict__ xout,
                            const float* __restrict__ Wlt, const float* __restrict__ Wrt,
                            const float* __restrict__ bl, int n_nodes) {
    __shared__ __align__(16) float A[TG][D];
    __shared__ __align__(16) float X[TG][D];
    int tid = threadIdx.x;
    int block0 = blockIdx.x * TG;

    // stage 32 rows of agg and x (1024 float4 each -> 4 per thread each)
    const float4* agg4 = (const float4*)(agg + (size_t)block0 * D);
    const float4* x4   = (const float4*)(xin + (size_t)block0 * D);
    float4* A4 = (float4*)A;
    float4* X4 = (float4*)X;
    int limit4 = (n_nodes - block0) * 32;   // float4s available in this tile
    #pragma unroll
    for (int t = 0; t < 4; ++t) {
        int i = t * 256 + tid;
        float4 za = {0,0,0,0}, zx = {0,0,0,0};
        if (i < limit4) { za = agg4[i]; zx = x4[i]; }
        A4[i] = za;
        X4[i] = zx;
    }
    __syncthreads();

    int tf = tid & 31;      // feature float4 index
    int tn = tid >> 5;      // node group 0..7 -> nodes tn*4..tn*4+3
    const float4* Wlt4 = (const float4*)Wlt;
    const float4* Wrt4 = (const float4*)Wrt;
    float4 bv = ((const float4*)bl)[tf];
    float4 acc[4];
    #pragma unroll
    for (int i = 0; i < 4; ++i) acc[i] = bv;

    int nbase = tn * 4;
    #pragma unroll 2
    for (int k = 0; k < D; k += 4) {
        float4 wl0 = Wlt4[(k + 0) * 32 + tf];
        float4 wl1 = Wlt4[(k + 1) * 32 + tf];
        float4 wl2 = Wlt4[(k + 2) * 32 + tf];
        float4 wl3 = Wlt4[(k + 3) * 32 + tf];
        float4 wr0 = Wrt4[(k + 0) * 32 + tf];
        float4 wr1 = Wrt4[(k + 1) * 32 + tf];
        float4 wr2 = Wrt4[(k + 2) * 32 + tf];
        float4 wr3 = Wrt4[(k + 3) * 32 + tf];
        #pragma unroll
        for (int i = 0; i < 4; ++i) {
            float4 a  = *(const float4*)&A[nbase + i][k];
            float4 xx = *(const float4*)&X[nbase + i][k];
            acc[i].x += wl0.x * a.x;  acc[i].y += wl0.y * a.x;
            acc[i].z += wl0.z * a.x;  acc[i].w += wl0.w * a.x;
            acc[i].x += wl1.x * a.y;  acc[i].y += wl1.y * a.y;
            acc[i].z += wl1.z * a.y;  acc[i].w += wl1.w * a.y;
            acc[i].x += wl2.x * a.z;  acc[i].y += wl2.y * a.z;
            acc[i].z += wl2.z * a.z;  acc[i].w += wl2.w * a.z;
            acc[i].x += wl3.x * a.w;  acc[i].y += wl3.y * a.w;
            acc[i].z += wl3.z * a.w;  acc[i].w += wl3.w * a.w;
            acc[i].x += wr0.x * xx.x; acc[i].y += wr0.y * xx.x;
            acc[i].z += wr0.z * xx.x; acc[i].w += wr0.w * xx.x;
            acc[i].x += wr1.x * xx.y; acc[i].y += wr1.y * xx.y;
            acc[i].z += wr1.z * xx.y; acc[i].w += wr1.w * xx.y;
            acc[i].x += wr2.x * xx.z; acc[i].y += wr2.y * xx.z;
            acc[i].z += wr2.z * xx.z; acc[i].w += wr2.w * xx.z;
            acc[i].x += wr3.x * xx.w; acc[i].y += wr3.y * xx.w;
            acc[i].z += wr3.z * xx.w; acc[i].w += wr3.w * xx.w;
        }
    }

    #pragma unroll
    for (int i = 0; i < 4; ++i) {
        int n = block0 + nbase + i;
        if (n < n_nodes) {
            float4 r;
            r.x = fmaxf(acc[i].x, 0.f);
            r.y = fmaxf(acc[i].y, 0.f);
            r.z = fmaxf(acc[i].z, 0.f);
            r.w = fmaxf(acc[i].w, 0.f);
            ((float4*)xout)[(size_t)n * 32 + tf] = r;
        }
    }
}

extern "C" void kernel_launch(void* const* d_in, const int* in_sizes, int n_in,
                              void* d_out, int out_size, void* d_ws, size_t ws_size,
                              hipStream_t stream) {
    const float* x  = (const float*)d_in[0];
    const int*  edge = (const int*)d_in[1];
    const float* Wl = (const float*)d_in[2];
    const float* bl = (const float*)d_in[3];
    const float* Wr = (const float*)d_in[4];

    int N = in_sizes[0] / D;
    int E = in_sizes[1] / 2;
    int L = in_sizes[3] / D;
    const int* srcp = edge;
    const int* dstp = edge + E;

    char* w = (char*)d_ws;
    auto alloc = [&](size_t bytes) {
        char* p = w;
        w += (bytes + 255) & ~(size_t)255;
        return p;
    };
    int*   deg       = (int*)alloc((size_t)N * 4);
    int*   local_ex  = (int*)alloc((size_t)N * 4);
    int*   row_start = (int*)alloc((size_t)(N + 1) * 4);
    int*   cursor    = (int*)alloc((size_t)N * 4);
    int*   csr       = (int*)alloc((size_t)E * 4);
    float* invdeg    = (float*)alloc((size_t)N * 4);
    int*   blocksum  = (int*)alloc((size_t)1024 * 4);
    float* wlt       = (float*)alloc((size_t)L * D * D * 4);
    float* wrt       = (float*)alloc((size_t)L * D * D * 4);
    float* buf0      = (float*)alloc((size_t)N * D * 4);
    float* aggbuf    = (float*)alloc((size_t)N * D * 4);

    int nb1 = (N + 1023) / 1024;
    hipMemsetAsync(deg, 0, (size_t)N * 4, stream);
    hist_kernel<<<(E + 255) / 256, 256, 0, stream>>>(dstp, deg, E);
    scan1_kernel<<<nb1, 1024, 0, stream>>>(deg, local_ex, blocksum, N);
    scan2_kernel<<<1, 1024, 0, stream>>>(blocksum, nb1);
    scan3_kernel<<<nb1, 1024, 0, stream>>>(deg, local_ex, blocksum, row_start,
                                           cursor, invdeg, N, E);
    scatter_kernel<<<(E + 255) / 256, 256, 0, stream>>>(srcp, dstp, cursor, csr, E);
    int tw = L * D * D;
    transpose_w<<<(tw + 255) / 256, 256, 0, stream>>>(Wl, Wr, wlt, wrt, tw);

    float* out = (float*)d_out;
    const float* cur = x;
    int nb_agg  = (N + TM - 1) / TM;
    int nb_gemm = (N + TG - 1) / TG;
    for (int l = 0; l < L; ++l) {
        float* o = (l & 1) ? out : buf0;
        if (l == L - 1) o = out;
        agg_kernel<<<nb_agg, 256, 0, stream>>>(cur, aggbuf, row_start, csr, invdeg, N);
        gemm_kernel<<<nb_gemm, 256, 0, stream>>>(aggbuf, cur, o,
                                                 wlt + (size_t)l * D * D,
                                                 wrt + (size_t)l * D * D,
                                                 bl + (size_t)l * D, N);
        cur = o;
    }
}